// Round 11
// baseline (131.906 us; speedup 1.0000x reference)
//
#include <hip/hip_runtime.h>

// ---------------------------------------------------------------------------
// BatchRelationalModule: b=16, c=64, L=256, F=64
// Factorization: layer0 pre-act = A[b,q,f] + B'[b,p,f]  (B' has bg0 folded in)
// Round 11: 32x32x16 MFMA restructure. One wave = 32 q, all 64 g/o.
// Per p: 8 MFMA (layer1) + 8 MFMA (layer2) for 32 q  -- half the MFMA instrs
// of the 16x16 path and full K-rate in layer2. Layer1 C/D -> layer2 B-operand
// via half-wave exchange (8 shfl_xor(32) + 16 cndmask), no LDS round-trip.
// Layouts: C/D verified (col=lane&31, row=(reg&3)+8*(reg>>2)+4*(lane>>5));
// A/B from the verified 16x16x32 family pattern (m=lane&31, k=(lane>>5)*8+j).
// ---------------------------------------------------------------------------

typedef short s8v __attribute__((ext_vector_type(8)));     // 8 x bf16 (4 VGPR)
typedef float f4v __attribute__((ext_vector_type(4)));     // 4 x f32
typedef float f16v __attribute__((ext_vector_type(16)));   // 32x32 MFMA C/D
typedef unsigned u4v __attribute__((ext_vector_type(4)));

#define KEEP(x) asm volatile("" : "+v"(x))   // opaque: forbids remat/sink

#define MFMA3216(a, b, c) __builtin_amdgcn_mfma_f32_32x32x16_bf16(a, b, c, 0, 0, 0)

// round-half-up f32->bf16 pair pack: (bits+0x8000) hi16s. <=0.5 ulp here.
__device__ __forceinline__ unsigned pkrh(float a, float b) {
  unsigned ua = __builtin_bit_cast(unsigned, a) + 0x8000u;
  unsigned ub = __builtin_bit_cast(unsigned, b) + 0x8000u;
  return (ua >> 16) | (ub & 0xFFFF0000u);
}
__device__ __forceinline__ float lo16f(unsigned w) {       // bf16 lo -> f32
  return __builtin_bit_cast(float, w << 16);
}
__device__ __forceinline__ float hi16f(unsigned w) {       // bf16 hi -> f32
  return __builtin_bit_cast(float, w & 0xFFFF0000u);
}
__device__ __forceinline__ f4v relu4(f4v v) {
  f4v z = {0.f, 0.f, 0.f, 0.f};
  return __builtin_elementwise_max(v, z);
}
__device__ __forceinline__ s8v cvt8(f4v a, f4v b) {
  u4v u = {pkrh(a[0], a[1]), pkrh(a[2], a[3]),
           pkrh(b[0], b[1]), pkrh(b[2], b[3])};
  return __builtin_bit_cast(s8v, u);
}
__device__ __forceinline__ f4v ldf4(const float* p) {
  return *(const f4v*)p;
}
__device__ __forceinline__ f16v zero16() {
  f16v v = {0.f,0.f,0.f,0.f,0.f,0.f,0.f,0.f,0.f,0.f,0.f,0.f,0.f,0.f,0.f,0.f};
  return v;
}

// ---------------------------------------------------------------------------
// Kernel 1: precompute A and B' (fp32).  (unchanged)
// ---------------------------------------------------------------------------
__global__ __launch_bounds__(256) void k_pre(
    const float* __restrict__ x, const float* __restrict__ Wg0,
    const float* __restrict__ bg0, float* __restrict__ Ag,
    float* __restrict__ Bg) {
  __shared__ float ws[64 * 131];
  __shared__ float xs[64 * 17];

  const int t = threadIdx.x;
  const int b = blockIdx.x >> 4;
  const int l0 = (blockIdx.x & 15) * 16;

  for (int i = t; i < 64 * 130; i += 256) {
    int f = i / 130, d = i - f * 130;
    ws[f * 131 + d] = Wg0[i];
  }
  for (int i = t; i < 64 * 16; i += 256) {
    int ch = i >> 4, li = i & 15;
    xs[ch * 17 + li] = x[b * 16384 + ch * 256 + l0 + li];
  }
  __syncthreads();

  const int f = t & 63;
  const int w = t >> 6;
  float accA[4] = {0.f, 0.f, 0.f, 0.f};
  float accB[4] = {0.f, 0.f, 0.f, 0.f};
  for (int d = 0; d < 64; ++d) {
    float wa = ws[f * 131 + d];
    float wb = ws[f * 131 + 65 + d];
#pragma unroll
    for (int i = 0; i < 4; ++i) {
      float xv = xs[d * 17 + w + 4 * i];
      accA[i] += xv * wa;
      accB[i] += xv * wb;
    }
  }
  const float wca = ws[f * 131 + 64];
  const float wcb = ws[f * 131 + 129];
  const float bias = bg0[f];
#pragma unroll
  for (int i = 0; i < 4; ++i) {
    int l = l0 + w + 4 * i;
    Ag[(b * 256 + l) * 64 + f] = accA[i] + (float)l * wca;
    Bg[(b * 256 + l) * 64 + f] = accB[i] + (float)l * wcb + bias;
  }
}

// ---------------------------------------------------------------------------
// Kernel 2: pair loop, 32x32 tiles. grid (32, 16) x 256 thr, bounds(256,1).
// blkx: qh = blkx&1 (q half: 128 q), pg = blkx>>1 (16 p). Wave: 32 q.
// ---------------------------------------------------------------------------
__global__ __launch_bounds__(256, 1) void k_main(
    const float* __restrict__ Ag, const float* __restrict__ Bg,
    const float* __restrict__ Wg1, const float* __restrict__ bg1,
    const float* __restrict__ Wg2, const float* __restrict__ bg2,
    float* __restrict__ Part) {
  __shared__ __align__(16) float Bs[16 * 64];   // 4 KB
  __shared__ float Sw[4][64];                   // per-wave partials

  const int t = threadIdx.x;
  const int wid = t >> 6;
  const int lane = t & 63;
  const int n = lane & 31;          // q col / m row
  const int h = lane >> 5;          // K-half selector
  const int b = blockIdx.y;
  const int blkx = blockIdx.x;      // 0..31
  const int qh = blkx & 1;
  const int p0 = (blkx >> 1) * 16;
  const int q = qh * 128 + wid * 32 + n;

  // ---- stage B'[16 rows] (4 KB) into LDS, coalesced dwordx4 ----
  {
    const f4v* Bb4 = (const f4v*)(Bg + (b * 256 + p0) * 64);
    ((f4v*)Bs)[t] = Bb4[t];
  }

  // ---- A row pinned: af[seg][half8]: A[q][f = seg*16 + h*8 + j] ----
  const float* Arow = Ag + (b * 256 + q) * 64 + h * 8;
  f4v af[4][2];
#pragma unroll
  for (int seg = 0; seg < 4; ++seg) {
    af[seg][0] = ldf4(Arow + seg * 16);
    af[seg][1] = ldf4(Arow + seg * 16 + 4);
  }

  // ---- weights, 32x32 A-operand: W[m = mt*32+n][k = seg*16 + h*8 + j] ----
  s8v W1A[2][4], W2A[2][4];
#pragma unroll
  for (int mt = 0; mt < 2; ++mt) {
#pragma unroll
    for (int seg = 0; seg < 4; ++seg) {
      const float* r1 = Wg1 + (mt * 32 + n) * 64 + seg * 16 + h * 8;
      const float* r2 = Wg2 + (mt * 32 + n) * 64 + seg * 16 + h * 8;
      W1A[mt][seg] = cvt8(ldf4(r1), ldf4(r1 + 4));
      W2A[mt][seg] = cvt8(ldf4(r2), ldf4(r2 + 4));
    }
  }

  // ---- biases packed bf16, dword d holds bias for C/D regs (2d, 2d+1):
  //      g(r) = mt*32 + (r&3) + 8*(r>>2) + 4*h ----
  u4v b1pv[2][2], b2pv[2][2];
#pragma unroll
  for (int mt = 0; mt < 2; ++mt) {
    const float* s1 = bg1 + mt * 32 + 4 * h;
    const float* s2 = bg2 + mt * 32 + 4 * h;
    f4v v0 = ldf4(s1), v1 = ldf4(s1 + 8), v2 = ldf4(s1 + 16), v3 = ldf4(s1 + 24);
    b1pv[mt][0] = (u4v){pkrh(v0[0], v0[1]), pkrh(v0[2], v0[3]),
                        pkrh(v1[0], v1[1]), pkrh(v1[2], v1[3])};
    b1pv[mt][1] = (u4v){pkrh(v2[0], v2[1]), pkrh(v2[2], v2[3]),
                        pkrh(v3[0], v3[1]), pkrh(v3[2], v3[3])};
    f4v u0 = ldf4(s2), u1 = ldf4(s2 + 8), u2 = ldf4(s2 + 16), u3 = ldf4(s2 + 24);
    b2pv[mt][0] = (u4v){pkrh(u0[0], u0[1]), pkrh(u0[2], u0[3]),
                        pkrh(u1[0], u1[1]), pkrh(u1[2], u1[3])};
    b2pv[mt][1] = (u4v){pkrh(u2[0], u2[1]), pkrh(u2[2], u2[3]),
                        pkrh(u3[0], u3[1]), pkrh(u3[2], u3[3])};
  }

  // ---- pin loop-invariants ----
#pragma unroll
  for (int mt = 0; mt < 2; ++mt) {
    KEEP(W1A[mt][0]); KEEP(W1A[mt][1]); KEEP(W1A[mt][2]); KEEP(W1A[mt][3]);
    KEEP(W2A[mt][0]); KEEP(W2A[mt][1]); KEEP(W2A[mt][2]); KEEP(W2A[mt][3]);
    KEEP(b1pv[mt][0]); KEEP(b1pv[mt][1]); KEEP(b2pv[mt][0]); KEEP(b2pv[mt][1]);
  }
#pragma unroll
  for (int seg = 0; seg < 4; ++seg) { KEEP(af[seg][0]); KEEP(af[seg][1]); }

  __syncthreads();   // Bs staged

  f16v cs[2] = {zero16(), zero16()};

#pragma unroll 2
  for (int ip = 0; ip < 16; ++ip) {
    // ---- B' frags (broadcast ds_read_b128: 2 addrs/wave = free) ----
    const float* br = Bs + ip * 64 + h * 8;
    // ---- X^T: B-operand, X[q=n][f = seg*16 + h*8 + j] = relu(A+B') ----
    s8v xb[4];
#pragma unroll
    for (int seg = 0; seg < 4; ++seg) {
      f4v b0 = ldf4(br + seg * 16);
      f4v b1 = ldf4(br + seg * 16 + 4);
      xb[seg] = cvt8(relu4(af[seg][0] + b0), relu4(af[seg][1] + b1));
    }

    // ---- layer 1: Y1[g][q], 2 m-tiles x K=64; bias folded at pack ----
    unsigned pk[2][8];
#pragma unroll
    for (int mt = 0; mt < 2; ++mt) {
      f16v u = zero16();
      u = MFMA3216(W1A[mt][0], xb[0], u);
      u = MFMA3216(W1A[mt][1], xb[1], u);
      u = MFMA3216(W1A[mt][2], xb[2], u);
      u = MFMA3216(W1A[mt][3], xb[3], u);
#pragma unroll
      for (int k = 0; k < 8; ++k) {
        unsigned w = b1pv[mt][k >> 2][k & 3];
        pk[mt][k] = pkrh(fmaxf(u[2 * k] + lo16f(w), 0.f),
                         fmaxf(u[2 * k + 1] + hi16f(w), 0.f));
      }
    }

    // ---- half-wave exchange: lane needs partner(lane^32)'s g-rows ----
    unsigned rcv[2][4];
#pragma unroll
    for (int mt = 0; mt < 2; ++mt) {
      unsigned w0 = h ? pk[mt][0] : pk[mt][2];
      unsigned w1 = h ? pk[mt][1] : pk[mt][3];
      unsigned w2 = h ? pk[mt][4] : pk[mt][6];
      unsigned w3 = h ? pk[mt][5] : pk[mt][7];
      rcv[mt][0] = __shfl_xor(w0, 32);
      rcv[mt][1] = __shfl_xor(w1, 32);
      rcv[mt][2] = __shfl_xor(w2, 32);
      rcv[mt][3] = __shfl_xor(w3, 32);
    }

    // ---- assemble layer-2 B-frags: Y1[g = seg*16 + h*8 + j][q=n] ----
    s8v y1b[4];
#pragma unroll
    for (int mt = 0; mt < 2; ++mt) {
      u4v ya = (u4v){h ? rcv[mt][0] : pk[mt][0],
                     h ? rcv[mt][1] : pk[mt][1],
                     h ? pk[mt][2] : rcv[mt][0],
                     h ? pk[mt][3] : rcv[mt][1]};
      u4v yb = (u4v){h ? rcv[mt][2] : pk[mt][4],
                     h ? rcv[mt][3] : pk[mt][5],
                     h ? pk[mt][6] : rcv[mt][2],
                     h ? pk[mt][7] : rcv[mt][3]};
      y1b[mt * 2]     = __builtin_bit_cast(s8v, ya);
      y1b[mt * 2 + 1] = __builtin_bit_cast(s8v, yb);
    }

    // ---- layer 2: Y2[o][q], bias folded at accumulate ----
#pragma unroll
    for (int ot = 0; ot < 2; ++ot) {
      f16v u = zero16();
      u = MFMA3216(W2A[ot][0], y1b[0], u);
      u = MFMA3216(W2A[ot][1], y1b[1], u);
      u = MFMA3216(W2A[ot][2], y1b[2], u);
      u = MFMA3216(W2A[ot][3], y1b[3], u);
#pragma unroll
      for (int k = 0; k < 16; ++k) {
        unsigned w = b2pv[ot][(k >> 1) >> 2][(k >> 1) & 3];
        float bb = (k & 1) ? hi16f(w) : lo16f(w);
        cs[ot][k] += fmaxf(u[k] + bb, 0.f);
      }
    }
  }

  // ---- reduce over q (32 lanes within each half; xor bits 0..4) ----
#pragma unroll
  for (int mt = 0; mt < 2; ++mt) {
#pragma unroll
    for (int m = 1; m < 32; m <<= 1) {
#pragma unroll
      for (int k = 0; k < 16; ++k)
        cs[mt][k] += __shfl_xor(cs[mt][k], m);
    }
  }
  if (n == 0) {        // lanes 0 and 32 write their 32 o-sums
#pragma unroll
    for (int mt = 0; mt < 2; ++mt)
#pragma unroll
      for (int r = 0; r < 16; ++r)
        Sw[wid][mt * 32 + (r & 3) + 8 * (r >> 2) + 4 * h] = cs[mt][r];
  }
  __syncthreads();
  if (t < 64)
    Part[(b * 32 + blkx) * 64 + t] =
        Sw[0][t] + Sw[1][t] + Sw[2][t] + Sw[3][t];
}

// ---------------------------------------------------------------------------
// Kernel 3: reduce 32 partials per (b,o), then f-network. grid 16 x 64.
// ---------------------------------------------------------------------------
__global__ __launch_bounds__(64) void k_final(
    const float* __restrict__ Part, const float* __restrict__ Wp,
    const float* __restrict__ bp, const float* __restrict__ Wo,
    const float* __restrict__ bo, float* __restrict__ out) {
  __shared__ float sv[64], tv[64];
  const int b = blockIdx.x, t = threadIdx.x;
  float s = 0.f;
  const float* Pb = Part + b * 32 * 64;
#pragma unroll
  for (int j = 0; j < 32; ++j) s += Pb[j * 64 + t];   // coalesced rows
  sv[t] = s;
  __syncthreads();
  float acc = bp[t];
  for (int g = 0; g < 64; ++g) acc += sv[g] * Wp[t * 64 + g];
  tv[t] = fmaxf(acc, 0.f);
  __syncthreads();
  float o = bo[t];
  for (int f = 0; f < 64; ++f) o += tv[f] * Wo[t * 64 + f];
  out[b * 64 + t] = o;
}

// ---------------------------------------------------------------------------
extern "C" void kernel_launch(void* const* d_in, const int* in_sizes, int n_in,
                              void* d_out, int out_size, void* d_ws, size_t ws_size,
                              hipStream_t stream) {
  const float* x   = (const float*)d_in[0];
  const float* Wg0 = (const float*)d_in[1];
  const float* bg0 = (const float*)d_in[2];
  const float* Wg1 = (const float*)d_in[3];
  const float* bg1 = (const float*)d_in[4];
  const float* Wg2 = (const float*)d_in[5];
  const float* bg2 = (const float*)d_in[6];
  const float* Wp  = (const float*)d_in[7];
  const float* bp  = (const float*)d_in[8];
  const float* Wo  = (const float*)d_in[9];
  const float* bo  = (const float*)d_in[10];
  float* out = (float*)d_out;

  float* Ag   = (float*)d_ws;            // [16][256][64] fp32 = 1 MB
  float* Bg   = Ag + 16 * 256 * 64;      // [16][256][64] fp32 = 1 MB
  float* Part = Bg + 16 * 256 * 64;      // [16][32][64] fp32 = 128 KB

  k_pre<<<256, 256, 0, stream>>>(x, Wg0, bg0, Ag, Bg);
  k_main<<<dim3(32, 16), 256, 0, stream>>>(Ag, Bg, Wg1, bg1, Wg2, bg2, Part);
  k_final<<<16, 64, 0, stream>>>(Part, Wp, bp, Wo, bo, out);
}